// Round 7
// baseline (174.007 us; speedup 1.0000x reference)
//
#include <hip/hip_runtime.h>
#include <math.h>

typedef float f32x2 __attribute__((ext_vector_type(2)));

#define LTOT 64
#define GL   16           // lanes per wavelength
#define LPL  4            // layers per lane

#define INV2PI  0.15915494309189535f
#define LOG2E   1.4426950408889634f
#define LOG10_2 0.30102999566398120f

// complex value for a packed pair of chains: lo = sigma=+1, hi = sigma=-1
struct C2 { f32x2 r, i; };
// transfer matrix in factored form [[A, iB],[iC, D]]
struct M2 { C2 A, B, C, D; };
// one wavelength's register-staged inputs (9 loads)
struct Regs {
    float4 ecr, eci, kcr, kci, ear, eai, kar, kai;
    float k0;
};

__device__ __forceinline__ f32x2 shx(f32x2 v, int m) {
    f32x2 r;
    r.x = __shfl_xor(v.x, m);
    r.y = __shfl_xor(v.y, m);
    return r;
}

// one layer for one stack, both sigmas packed: P = P @ M_layer (or P = M if first)
__device__ __forceinline__ void layer_stack(M2& M, bool first, float kd,
                                            float er, float ei, float kr, float ki) {
    // n0 = sqrt(eps) (principal, er>0, ei>=0), inv = 1/|n0|^2 = 1/|eps|
    float h2  = fmaf(er, er, ei * ei);
    float inv = __builtin_amdgcn_rsqf(h2);       // 1/|eps|
    float mm  = h2 * inv;                        // |eps|
    float x   = 0.5f * (mm + er);
    float rx  = __builtin_amdgcn_rsqf(x);
    float n0r = x * rx;
    float n0i = 0.5f * ei * rx;

    float ar = kd * n0r, ai = kd * n0i;   // a = kd * n0
    float br = kd * kr,  bi = kd * ki;    // b = kd * kappa (|br| <= ~0.024)

    // trig of a_r (native, revolutions); small-angle polys for b_r
    float rf = __builtin_amdgcn_fractf(ar * INV2PI);
    float sa = __builtin_amdgcn_sinf(rf);
    float ca = __builtin_amdgcn_cosf(rf);
    float b2 = br * br;
    float sb = br * fmaf(b2, -0.16666667f, 1.0f);
    float cb = fmaf(b2, -0.5f, 1.0f);
    float u = sa * cb, v = ca * sb, wq = ca * cb, zq = sa * sb;

    f32x2 S, Cx, Y;
    S.x = u + v;   S.y = u - v;     // sin(ar +/- br)
    Cx.x = wq - zq; Cx.y = wq + zq; // cos(ar +/- br)
    Y.x = ai + bi; Y.y = ai - bi;   // Im(delta), |Y| <= ~0.17

    // cosh/sinh by poly (err < 3e-8 on this range)
    f32x2 y2 = Y * Y;
    f32x2 ch = (y2 * 0.041666667f + 0.5f) * y2 + 1.0f;
    f32x2 sh = Y * ((y2 * 0.0083333333f + 0.16666667f) * y2 + 1.0f);

    // cos(delta) = (Cx*ch, -S*sh) ; sin(delta) = (S*ch, Cx*sh)
    f32x2 c_r = Cx * ch;
    f32x2 c_i = -(S * sh);
    f32x2 s_r = S * ch;
    f32x2 s_i = Cx * sh;

    // q = s * conj(n0) * inv  (so m01 = i q) ; p = n0 * s (so m10 = i p)
    f32x2 q_r = (s_r * n0r + s_i * n0i) * inv;
    f32x2 q_i = (s_i * n0r - s_r * n0i) * inv;
    f32x2 p_r = s_r * n0r - s_i * n0i;
    f32x2 p_i = s_i * n0r + s_r * n0i;

    if (first) {
        M.A.r = c_r; M.A.i = c_i;
        M.B.r = q_r; M.B.i = q_i;
        M.C.r = p_r; M.C.i = p_i;
        M.D.r = c_r; M.D.i = c_i;
    } else {
        // A' = A c - B p ; B' = A q + B c ; C' = C c + D p ; D' = D c - C q
        f32x2 nAr = M.A.r*c_r - M.A.i*c_i - M.B.r*p_r + M.B.i*p_i;
        f32x2 nAi = M.A.r*c_i + M.A.i*c_r - M.B.r*p_i - M.B.i*p_r;
        f32x2 nBr = M.A.r*q_r - M.A.i*q_i + M.B.r*c_r - M.B.i*c_i;
        f32x2 nBi = M.A.r*q_i + M.A.i*q_r + M.B.r*c_i + M.B.i*c_r;
        f32x2 nCr = M.C.r*c_r - M.C.i*c_i + M.D.r*p_r - M.D.i*p_i;
        f32x2 nCi = M.C.r*c_i + M.C.i*c_r + M.D.r*p_i + M.D.i*p_r;
        f32x2 nDr = M.D.r*c_r - M.D.i*c_i - M.C.r*q_r + M.C.i*q_i;
        f32x2 nDi = M.D.r*c_i + M.D.i*c_r - M.C.r*q_i - M.C.i*q_r;
        M.A.r = nAr; M.A.i = nAi; M.B.r = nBr; M.B.i = nBi;
        M.C.r = nCr; M.C.i = nCi; M.D.r = nDr; M.D.i = nDi;
    }
}

// L = L · R in factored form:
// A = Al Ar - Bl Cr ; B = Al Br + Bl Dr ; C = Cl Ar + Dl Cr ; D = Dl Dr - Cl Br
__device__ __forceinline__ void combine(M2& L, const M2& R) {
    f32x2 nAr = L.A.r*R.A.r - L.A.i*R.A.i - L.B.r*R.C.r + L.B.i*R.C.i;
    f32x2 nAi = L.A.r*R.A.i + L.A.i*R.A.r - L.B.r*R.C.i - L.B.i*R.C.r;
    f32x2 nBr = L.A.r*R.B.r - L.A.i*R.B.i + L.B.r*R.D.r - L.B.i*R.D.i;
    f32x2 nBi = L.A.r*R.B.i + L.A.i*R.B.r + L.B.r*R.D.i + L.B.i*R.D.r;
    f32x2 nCr = L.C.r*R.A.r - L.C.i*R.A.i + L.D.r*R.C.r - L.D.i*R.C.i;
    f32x2 nCi = L.C.r*R.A.i + L.C.i*R.A.r + L.D.r*R.C.i + L.D.i*R.C.r;
    f32x2 nDr = L.D.r*R.D.r - L.D.i*R.D.i - L.C.r*R.B.r + L.C.i*R.B.i;
    f32x2 nDi = L.D.r*R.D.i + L.D.i*R.D.r - L.C.r*R.B.i - L.C.i*R.B.r;
    L.A.r = nAr; L.A.i = nAi; L.B.r = nBr; L.B.i = nBi;
    L.C.r = nCr; L.C.i = nCi; L.D.r = nDr; L.D.i = nDi;
}

__device__ __forceinline__ M2 shfl_m2(const M2& M, int m) {
    M2 R;
    R.A.r = shx(M.A.r, m); R.A.i = shx(M.A.i, m);
    R.B.r = shx(M.B.r, m); R.B.i = shx(M.B.i, m);
    R.C.r = shx(M.C.r, m); R.C.i = shx(M.C.i, m);
    R.D.r = shx(M.D.r, m); R.D.i = shx(M.D.i, m);
    return R;
}

__device__ __forceinline__ Regs load_all(
    const float* __restrict__ wl,
    const float* __restrict__ ecr, const float* __restrict__ eci,
    const float* __restrict__ kcr, const float* __restrict__ kci,
    const float* __restrict__ ear, const float* __restrict__ eai,
    const float* __restrict__ kar, const float* __restrict__ kai,
    size_t base, int w)
{
    Regs R;
    R.ecr = *reinterpret_cast<const float4*>(ecr + base);
    R.eci = *reinterpret_cast<const float4*>(eci + base);
    R.kcr = *reinterpret_cast<const float4*>(kcr + base);
    R.kci = *reinterpret_cast<const float4*>(kci + base);
    R.ear = *reinterpret_cast<const float4*>(ear + base);
    R.eai = *reinterpret_cast<const float4*>(eai + base);
    R.kar = *reinterpret_cast<const float4*>(kar + base);
    R.kai = *reinterpret_cast<const float4*>(kai + base);
    R.k0  = 6.2831852e6f * __builtin_amdgcn_rcpf(wl[w]);
    return R;
}

__device__ __forceinline__ void layers(const Regs& R, const float* dq, M2& Mc, M2& Ma)
{
    const float* pecr = reinterpret_cast<const float*>(&R.ecr);
    const float* peci = reinterpret_cast<const float*>(&R.eci);
    const float* pkcr = reinterpret_cast<const float*>(&R.kcr);
    const float* pkci = reinterpret_cast<const float*>(&R.kci);
    const float* pear = reinterpret_cast<const float*>(&R.ear);
    const float* peai = reinterpret_cast<const float*>(&R.eai);
    const float* pkar = reinterpret_cast<const float*>(&R.kar);
    const float* pkai = reinterpret_cast<const float*>(&R.kai);
    #pragma unroll
    for (int q = 0; q < LPL; q++) {
        bool first = (q == 0);
        float kd = R.k0 * dq[q];
        layer_stack(Mc, first, kd, pecr[q], peci[q], pkcr[q], pkci[q]);
        layer_stack(Ma, first, kd, pear[q], peai[q], pkar[q], pkai[q]);
    }
}

__device__ __forceinline__ void reduce_store(M2 Mc, M2 Ma, int j, int w, int W,
                                             float* __restrict__ out)
{
    // select-free ordered reduction: P = P * shfl_xor(P, m).
    // Lanes with (j mod 2m)==0 hold the correct left-to-right product;
    // lane 0 ends with the full 64-layer product.
    #pragma unroll
    for (int m = 1; m < GL; m <<= 1) {
        M2 Oc = shfl_m2(Mc, m);
        M2 Oa = shfl_m2(Ma, m);
        combine(Mc, Oc);
        combine(Ma, Oa);
    }

    if (j == 0) {
        const float NOUT = 1.45f;
        // denom = A + i*NOUT*B + i*C + NOUT*D  (N_IN = 1)
        f32x2 drc = Mc.A.r + NOUT * Mc.D.r - NOUT * Mc.B.i - Mc.C.i;
        f32x2 dic = Mc.A.i + NOUT * Mc.D.i + NOUT * Mc.B.r + Mc.C.r;
        f32x2 dra = Ma.A.r + NOUT * Ma.D.r - NOUT * Ma.B.i - Ma.C.i;
        f32x2 dia = Ma.A.i + NOUT * Ma.D.i + NOUT * Ma.B.r + Ma.C.r;
        f32x2 denc = drc * drc + dic * dic;
        f32x2 dena = dra * dra + dia * dia;
        // T = 4*NOUT/|den|^2 = 5.8/|den|^2 ; A = -log10(T + 1e-12)
        float Arc = -LOG10_2 * __builtin_amdgcn_logf(5.8f * __builtin_amdgcn_rcpf(denc.x) + 1e-12f);
        float Alc = -LOG10_2 * __builtin_amdgcn_logf(5.8f * __builtin_amdgcn_rcpf(denc.y) + 1e-12f);
        float Ara = -LOG10_2 * __builtin_amdgcn_logf(5.8f * __builtin_amdgcn_rcpf(dena.x) + 1e-12f);
        float Ala = -LOG10_2 * __builtin_amdgcn_logf(5.8f * __builtin_amdgcn_rcpf(dena.y) + 1e-12f);

        const float SC = (2.0f * 0.87f - 1.0f) * 32980.0f;
        out[0 * W + w] = (Alc - Arc) * SC;   // cd_c * scale
        out[1 * W + w] = (Ala - Ara) * SC;   // cd_a * scale
        out[2 * W + w] = 0.5f * (Alc + Arc); // abs_c
        out[3 * W + w] = 0.5f * (Ala + Ara); // abs_a
    }
}

__global__ __launch_bounds__(256, 4) void chiral_kernel(
    const float* __restrict__ wl,  const float* __restrict__ thickP,
    const float* __restrict__ mindp, const float* __restrict__ maxdp,
    const float* __restrict__ ecr, const float* __restrict__ eci,
    const float* __restrict__ kcr, const float* __restrict__ kci,
    const float* __restrict__ ear, const float* __restrict__ eai,
    const float* __restrict__ kar, const float* __restrict__ kai,
    float* __restrict__ out, int W)
{
    int t  = blockIdx.x * blockDim.x + threadIdx.x;
    int Wh = W >> 1;
    int w0 = t >> 4;      // one 16-lane group per wavelength
    int j  = t & 15;      // lane owns layers 4j..4j+3
    if (w0 >= Wh) return;
    int w1 = w0 + Wh;

    size_t b0 = (size_t)w0 * LTOT + (size_t)(LPL * j);
    size_t b1 = (size_t)w1 * LTOT + (size_t)(LPL * j);

    // ---- region 1: iter-0 loads + layer-only thickness precompute ----
    Regs R0 = load_all(wl, ecr, eci, kcr, kci, ear, eai, kar, kai, b0, w0);

    float lo = mindp[0], hi = maxdp[0];
    float4 tp4 = *reinterpret_cast<const float4*>(thickP + LPL * j);
    const float* ptp = reinterpret_cast<const float*>(&tp4);
    float dq[LPL];
    #pragma unroll
    for (int q = 0; q < LPL; q++) {
        float sg = __builtin_amdgcn_rcpf(1.0f + __builtin_amdgcn_exp2f(-ptp[q] * LOG2E));
        dq[q] = fmaf(sg, hi - lo, lo) * 1e-9f;   // shared by both wavelengths
    }
    __builtin_amdgcn_sched_barrier(0);   // pin loads above compute

    // ---- region 2: iter-1 loads overlap iter-0 layer chain ----
    Regs R1 = load_all(wl, ecr, eci, kcr, kci, ear, eai, kar, kai, b1, w1);
    M2 Mc0, Ma0;
    layers(R0, dq, Mc0, Ma0);
    __builtin_amdgcn_sched_barrier(0);   // keep R1 issue inside region 2

    // ---- region 3: iter-0 butterfly interleaves with iter-1 layer chain ----
    reduce_store(Mc0, Ma0, j, w0, W, out);
    M2 Mc1, Ma1;
    layers(R1, dq, Mc1, Ma1);
    reduce_store(Mc1, Ma1, j, w1, W, out);
}

extern "C" void kernel_launch(void* const* d_in, const int* in_sizes, int n_in,
                              void* d_out, int out_size, void* d_ws, size_t ws_size,
                              hipStream_t stream) {
    const float* wl     = (const float*)d_in[0];
    const float* thickP = (const float*)d_in[1];
    const float* mind   = (const float*)d_in[2];
    const float* maxd   = (const float*)d_in[3];
    const float* ecr    = (const float*)d_in[4];
    const float* eci    = (const float*)d_in[5];
    const float* kcr    = (const float*)d_in[6];
    const float* kci    = (const float*)d_in[7];
    const float* ear    = (const float*)d_in[8];
    const float* eai    = (const float*)d_in[9];
    const float* kar    = (const float*)d_in[10];
    const float* kai    = (const float*)d_in[11];
    float* out = (float*)d_out;

    int W = in_sizes[0];
    int threads = (W / 2) * GL;          // two wavelengths per thread
    int block = 256;
    int grid = (threads + block - 1) / block;
    chiral_kernel<<<grid, block, 0, stream>>>(wl, thickP, mind, maxd,
                                              ecr, eci, kcr, kci,
                                              ear, eai, kar, kai, out, W);
}